// Round 5
// baseline (1741.100 us; speedup 1.0000x reference)
//
#include <hip/hip_runtime.h>
#include <hip/hip_bf16.h>
#include <cstdint>
#include <cstddef>

#define D_DIM 128

typedef __attribute__((ext_vector_type(8))) short short8;
typedef __attribute__((ext_vector_type(4))) float f32x4;

__device__ __forceinline__ float sigmoid_fast(float z) {
  return __builtin_amdgcn_rcpf(1.0f + __expf(-z));
}

__device__ __forceinline__ unsigned short f2bf(float f) {
  union { float f; unsigned u; } v; v.f = f;
  unsigned r = v.u + 0x7FFF + ((v.u >> 16) & 1);   // RNE
  return (unsigned short)(r >> 16);
}
__device__ __forceinline__ float bf_lo(unsigned u) { return __uint_as_float(u << 16); }
__device__ __forceinline__ float bf_hi(unsigned u) { return __uint_as_float(u & 0xFFFF0000u); }

// Convert 6 [128x128] f32 weight matrices to bf16, contiguous in dst.
__global__ __launch_bounds__(256) void wconv_kernel(
    const float* __restrict__ s0, const float* __restrict__ s1, const float* __restrict__ s2,
    const float* __restrict__ s3, const float* __restrict__ s4, const float* __restrict__ s5,
    short* __restrict__ dst) {
  int idx = blockIdx.x * 256 + threadIdx.x;
  int mat = idx >> 12;
  int pos = (idx & 4095) * 4;
  const float* s = (mat == 0) ? s0 : (mat == 1) ? s1 : (mat == 2) ? s2
                 : (mat == 3) ? s3 : (mat == 4) ? s4 : s5;
  float4 f = *(const float4*)(s + pos);
  short4 o;
  o.x = (short)f2bf(f.x); o.y = (short)f2bf(f.y);
  o.z = (short)f2bf(f.z); o.w = (short)f2bf(f.w);
  *(short4*)(dst + mat * 16384 + pos) = o;
}

// Per-node MFMA precompute. Block = 4 waves covering 32 nodes.
__global__ __launch_bounds__(256) void node_mfma_kernel(
    const float* __restrict__ x,
    const short* __restrict__ Wmnb, const short* __restrict__ Wgnb, const short* __restrict__ Wsb,
    const float* __restrict__ bmn, const float* __restrict__ bme,
    const float* __restrict__ bgn, const float* __restrict__ bge,
    const float* __restrict__ bs, const float* __restrict__ bias_other,
    unsigned int* __restrict__ YG, float* __restrict__ out_init, int n) {
  __shared__ unsigned sh[32][132];
  const int t = threadIdx.x;
  const int wave = t >> 6, lane = t & 63;
  const int q = lane >> 4, l15 = lane & 15;
  const int ng = wave >> 1;
  const int h = (wave & 1) * 64;
  const int base_node = blockIdx.x * 32;
  const int node_base = base_node + ng * 16;

  short8 a[4];
  {
    int m = node_base + l15;
    int mc = m < n ? m : (n - 1);
    const float* xrow = x + (size_t)mc * D_DIM;
#pragma unroll
    for (int ks = 0; ks < 4; ++ks) {
      float4 f0 = *(const float4*)(xrow + ks * 32 + q * 8);
      float4 f1 = *(const float4*)(xrow + ks * 32 + q * 8 + 4);
      union { short8 s; __hip_bfloat162 hh[4]; } u;
      u.hh[0] = __float22bfloat162_rn({f0.x, f0.y});
      u.hh[1] = __float22bfloat162_rn({f0.z, f0.w});
      u.hh[2] = __float22bfloat162_rn({f1.x, f1.y});
      u.hh[3] = __float22bfloat162_rn({f1.z, f1.w});
      a[ks] = u.s;
    }
  }

  f32x4 accY[4], accG[4], accS[4];
#pragma unroll
  for (int nt = 0; nt < 4; ++nt) { accY[nt] = {0,0,0,0}; accG[nt] = {0,0,0,0}; accS[nt] = {0,0,0,0}; }

#pragma unroll
  for (int nt = 0; nt < 4; ++nt) {
    const int row = h + nt * 16 + l15;
#pragma unroll
    for (int ks = 0; ks < 4; ++ks) {
      const int off = row * D_DIM + ks * 32 + q * 8;
      short8 bm  = *(const short8*)(Wmnb + off);
      short8 bg  = *(const short8*)(Wgnb + off);
      short8 bsw = *(const short8*)(Wsb + off);
      accY[nt] = __builtin_amdgcn_mfma_f32_16x16x32_bf16(a[ks], bm,  accY[nt], 0, 0, 0);
      accG[nt] = __builtin_amdgcn_mfma_f32_16x16x32_bf16(a[ks], bg,  accG[nt], 0, 0, 0);
      accS[nt] = __builtin_amdgcn_mfma_f32_16x16x32_bf16(a[ks], bsw, accS[nt], 0, 0, 0);
    }
  }

#pragma unroll
  for (int nt = 0; nt < 4; ++nt) {
    int d = h + nt * 16 + l15;
    float bmv = bmn[d] + bme[d];
    float bgv = bgn[d] + bge[d];
#pragma unroll
    for (int r = 0; r < 4; ++r) {
      union { __hip_bfloat162 hh; unsigned u; } pck;
      pck.hh = __float22bfloat162_rn({accY[nt][r] + bmv, accG[nt][r] + bgv});
      sh[ng * 16 + q * 4 + r][d] = pck.u;
    }
  }
  __syncthreads();
#pragma unroll
  for (int it = 0; it < 4; ++it) {
    int idx = (it * 256 + t) * 4;
    int nl = idx >> 7, dd = idx & 127;
    int node = base_node + nl;
    if (node < n)
      *(uint4*)(YG + (size_t)node * D_DIM + dd) = *(const uint4*)&sh[nl][dd];
  }
  __syncthreads();

  float* shf = (float*)sh;
#pragma unroll
  for (int nt = 0; nt < 4; ++nt) {
    int d = h + nt * 16 + l15;
    float bsv = bs[d];
#pragma unroll
    for (int r = 0; r < 4; ++r)
      shf[(ng * 16 + q * 4 + r) * 132 + d] = sigmoid_fast(accS[nt][r] + bsv) + 0.5f;
  }
  __syncthreads();
#pragma unroll
  for (int it = 0; it < 4; ++it) {
    int idx = (it * 256 + t) * 4;
    int nl = idx >> 7, dd = idx & 127;
    int node = base_node + nl;
    if (node < n) {
      float4 xv = *(const float4*)(x + (size_t)node * D_DIM + dd);
      float4 bo = *(const float4*)(bias_other + dd);
      const float* sp = &shf[nl * 132 + dd];
      float4 o;
      o.x = sp[0] * xv.x + bo.x;
      o.y = sp[1] * xv.y + bo.y;
      o.z = sp[2] * xv.z + bo.z;
      o.w = sp[3] * xv.w + bo.w;
      *(float4*)(out_init + (size_t)node * D_DIM + dd) = o;
    }
  }
}

// ---------- counting sort (coarse only) + fused bucket gather ----------
// Buckets of 64 dsts for both types. Combined bucket id: task b = dst>>6,
// data b = NBT + (dst>>6). loc = dst & 63 packed into ef's low mantissa bits.

__global__ __launch_bounds__(256) void hist0_kernel(
    const int* __restrict__ dst_dt, const int* __restrict__ dst_td,
    int* __restrict__ ghist, int nbt, int NB, int E) {
  __shared__ int lh[2048];
  int t = threadIdx.x;
#pragma unroll
  for (int k = 0; k < 8; ++k) lh[t + k * 256] = 0;
  __syncthreads();
  for (int i = blockIdx.x * 256 + t; i < E; i += gridDim.x * 256) {
    atomicAdd(&lh[dst_dt[i] >> 6], 1);
    atomicAdd(&lh[nbt + (dst_td[i] >> 6)], 1);
  }
  __syncthreads();
#pragma unroll
  for (int k = 0; k < 8; ++k) {
    int b = t + k * 256;
    int c = lh[b];
    if (b < NB && c) atomicAdd(&ghist[b], c);
  }
}

// Scan NB (<2048) bucket counts -> bases + cursors.
__global__ __launch_bounds__(256) void bucket_scan_kernel(
    const int* __restrict__ ghist, int* __restrict__ bbase, int* __restrict__ bcur, int NB) {
  __shared__ int sc[256];
  int t = threadIdx.x;
  int i0 = t * 8;
  int c[8]; int tot = 0;
#pragma unroll
  for (int k = 0; k < 8; ++k) { c[k] = (i0 + k < NB) ? ghist[i0 + k] : 0; tot += c[k]; }
  sc[t] = tot; __syncthreads();
  for (int s = 1; s < 256; s <<= 1) {
    int u = (t >= s) ? sc[t - s] : 0;
    __syncthreads(); sc[t] += u; __syncthreads();
  }
  int run = sc[t] - tot;
#pragma unroll
  for (int k = 0; k < 8; ++k) {
    if (i0 + k < NB) { bbase[i0 + k] = run; bcur[i0 + k] = run; }
    run += c[k];
  }
  if (t == 255) bbase[NB] = run;
}

// Coarse partition: block handles 4096 edges of each list; one global atomicAdd
// per touched bucket reserves a contiguous run. Entry = {src, ef_hi24|loc6}.
__global__ __launch_bounds__(256) void sort_a_kernel(
    const int* __restrict__ src_dt, const int* __restrict__ dst_dt, const float* __restrict__ ef_dt,
    const int* __restrict__ src_td, const int* __restrict__ dst_td, const float* __restrict__ ef_td,
    int* __restrict__ bcur, int2* __restrict__ eA, int nbt, int NB, int E) {
  __shared__ int lh[2048];
  __shared__ int lcur[2048];
  int t = threadIdx.x;
#pragma unroll
  for (int k = 0; k < 8; ++k) lh[t + k * 256] = 0;
  __syncthreads();
  int e0 = blockIdx.x * 4096;
  int e1 = min(E, e0 + 4096);
  for (int i = e0 + t; i < e1; i += 256) {
    atomicAdd(&lh[dst_dt[i] >> 6], 1);
    atomicAdd(&lh[nbt + (dst_td[i] >> 6)], 1);
  }
  __syncthreads();
#pragma unroll
  for (int k = 0; k < 8; ++k) {
    int b = t + k * 256;
    int c = lh[b];
    if (b < NB && c) lcur[b] = atomicAdd(&bcur[b], c);
  }
  __syncthreads();
  for (int i = e0 + t; i < e1; i += 256) {
    int c = dst_dt[i];
    int pos = atomicAdd(&lcur[c >> 6], 1);
    eA[pos] = make_int2(src_dt[i],
        (int)((__float_as_uint(ef_dt[i]) & 0xFFFFFF00u) | (unsigned)(c & 63)));
    int cd = dst_td[i];
    int pos2 = atomicAdd(&lcur[nbt + (cd >> 6)], 1);
    eA[pos2] = make_int2(src_td[i],
        (int)((__float_as_uint(ef_td[i]) & 0xFFFFFF00u) | (unsigned)(cd & 63)));
  }
}

// Fused gather: one block per bucket. 64x128 f32 LDS accumulator; one wave per
// edge (lane i -> dims i, i+64; stride-1 LDS, conflict-free); ds_add_f32
// accumulate; coalesced epilogue out = relu(out_init + accum) over the
// bucket's contiguous 64 output rows.
__global__ __launch_bounds__(256) void gather_bucket_kernel(
    const unsigned* __restrict__ YG_dt, const unsigned* __restrict__ YG_td,
    const int* __restrict__ bbase, const int2* __restrict__ eA,
    const float* __restrict__ Wme_dt, const float* __restrict__ Wge_dt,
    const float* __restrict__ Wme_td, const float* __restrict__ Wge_td,
    float* __restrict__ out, int nbt, int n_task, int n_data) {
  __shared__ float accum[64 * 128];                // 32 KB
  const int b = blockIdx.x, t = threadIdx.x;
  const int wave = t >> 6, lane = t & 63;
  const bool is_dt = b < nbt;
  const unsigned* YG = is_dt ? YG_dt : YG_td;
  const float* Wme = is_dt ? Wme_dt : Wme_td;
  const float* Wge = is_dt ? Wge_dt : Wge_td;
  const int d0 = is_dt ? (b << 6) : ((b - nbt) << 6);        // first dst of bucket
  const int row0 = is_dt ? (n_data + d0) : d0;               // first out row
  const int nloc = is_dt ? min(64, n_task - d0) : min(64, n_data - d0);

#pragma unroll
  for (int k = 0; k < 8; ++k)
    *(float4*)&accum[(k * 256 + t) * 4] = {0.f, 0.f, 0.f, 0.f};

  const float wme0 = Wme[lane], wme1 = Wme[lane + 64];
  const float wge0 = Wge[lane], wge1 = Wge[lane + 64];
  __syncthreads();

  const int base = bbase[b], end = bbase[b + 1];
  int p = base + wave;
  for (; p + 4 < end; p += 8) {                    // 2 edges in flight per wave
    int2 ea = eA[p], eb = eA[p + 4];
    size_t ra = (size_t)ea.x << 7, rb = (size_t)eb.x << 7;
    unsigned a0 = YG[ra + lane], a1 = YG[ra + lane + 64];
    unsigned b0 = YG[rb + lane], b1 = YG[rb + lane + 64];
    float fa = __int_as_float(ea.y & (int)0xFFFFFF00);
    float fb = __int_as_float(eb.y & (int)0xFFFFFF00);
    int la = ea.y & 63, lb = eb.y & 63;
    float ga0 = sigmoid_fast(fmaf(fa, wge0, bf_hi(a0))) - 0.5f;
    float ga1 = sigmoid_fast(fmaf(fa, wge1, bf_hi(a1))) - 0.5f;
    float ma0 = fmaf(fa, wme0, bf_lo(a0)) * ga0;
    float ma1 = fmaf(fa, wme1, bf_lo(a1)) * ga1;
    atomicAdd(&accum[la * 128 + lane], ma0);
    atomicAdd(&accum[la * 128 + lane + 64], ma1);
    float gb0 = sigmoid_fast(fmaf(fb, wge0, bf_hi(b0))) - 0.5f;
    float gb1 = sigmoid_fast(fmaf(fb, wge1, bf_hi(b1))) - 0.5f;
    float mb0 = fmaf(fb, wme0, bf_lo(b0)) * gb0;
    float mb1 = fmaf(fb, wme1, bf_lo(b1)) * gb1;
    atomicAdd(&accum[lb * 128 + lane], mb0);
    atomicAdd(&accum[lb * 128 + lane + 64], mb1);
  }
  for (; p < end; p += 4) {
    int2 ea = eA[p];
    size_t ra = (size_t)ea.x << 7;
    unsigned a0 = YG[ra + lane], a1 = YG[ra + lane + 64];
    float fa = __int_as_float(ea.y & (int)0xFFFFFF00);
    int la = ea.y & 63;
    float ga0 = sigmoid_fast(fmaf(fa, wge0, bf_hi(a0))) - 0.5f;
    float ga1 = sigmoid_fast(fmaf(fa, wge1, bf_hi(a1))) - 0.5f;
    atomicAdd(&accum[la * 128 + lane], fmaf(fa, wme0, bf_lo(a0)) * ga0);
    atomicAdd(&accum[la * 128 + lane + 64], fmaf(fa, wme1, bf_lo(a1)) * ga1);
  }
  __syncthreads();

#pragma unroll
  for (int k = 0; k < 8; ++k) {
    int idx = (k * 256 + t) * 4;                   // float index in [0, 8192)
    int loc = idx >> 7, dd = idx & 127;
    if (loc < nloc) {
      float* op = out + (size_t)(row0 + loc) * D_DIM + dd;
      float4 ov = *(const float4*)op;              // self + conv-bias
      float4 av = *(const float4*)&accum[loc * 128 + dd];
      float4 r;
      r.x = fmaxf(ov.x + av.x, 0.f);
      r.y = fmaxf(ov.y + av.y, 0.f);
      r.z = fmaxf(ov.z + av.z, 0.f);
      r.w = fmaxf(ov.w + av.w, 0.f);
      *(float4*)op = r;
    }
  }
}

extern "C" void kernel_launch(void* const* d_in, const int* in_sizes, int n_in,
                              void* d_out, int out_size, void* d_ws, size_t ws_size,
                              hipStream_t stream) {
  const float* x_data  = (const float*)d_in[0];
  const float* x_task  = (const float*)d_in[1];
  const int*   src_dt  = (const int*)d_in[2];
  const int*   dst_dt  = (const int*)d_in[3];
  const float* ef_dt   = (const float*)d_in[4];
  const int*   src_td  = (const int*)d_in[5];
  const int*   dst_td  = (const int*)d_in[6];
  const float* ef_td   = (const float*)d_in[7];
  const float* Wmn_dt  = (const float*)d_in[8];
  const float* bmn_dt  = (const float*)d_in[9];
  const float* Wme_dt  = (const float*)d_in[10];
  const float* bme_dt  = (const float*)d_in[11];
  const float* Wgn_dt  = (const float*)d_in[12];
  const float* bgn_dt  = (const float*)d_in[13];
  const float* Wge_dt  = (const float*)d_in[14];
  const float* bge_dt  = (const float*)d_in[15];
  const float* bias_dt = (const float*)d_in[16];
  const float* Wmn_td  = (const float*)d_in[17];
  const float* bmn_td  = (const float*)d_in[18];
  const float* Wme_td  = (const float*)d_in[19];
  const float* bme_td  = (const float*)d_in[20];
  const float* Wgn_td  = (const float*)d_in[21];
  const float* bgn_td  = (const float*)d_in[22];
  const float* Wge_td  = (const float*)d_in[23];
  const float* bge_td  = (const float*)d_in[24];
  const float* bias_td = (const float*)d_in[25];
  const float* Ws_data = (const float*)d_in[26];
  const float* bs_data = (const float*)d_in[27];
  const float* Ws_task = (const float*)d_in[28];
  const float* bs_task = (const float*)d_in[29];
  float* out = (float*)d_out;

  const int N_DATA = in_sizes[0] / D_DIM;   // 100000
  const int N_TASK = in_sizes[1] / D_DIM;   // 20000
  const int E = in_sizes[2];                // 1000000
  const int NBT = (N_TASK + 63) >> 6;       // 313
  const int NBD = (N_DATA + 63) >> 6;       // 1563
  const int NB = NBT + NBD;                 // 1876

  char* ws = (char*)d_ws;
  size_t off = 0;
  auto alloc = [&](size_t bytes) { void* p = ws + off; off += (bytes + 255) & ~(size_t)255; return p; };
  unsigned int* YG_dt = (unsigned int*)alloc((size_t)N_DATA * D_DIM * 4);
  unsigned int* YG_td = (unsigned int*)alloc((size_t)N_TASK * D_DIM * 4);
  int2* eA     = (int2*)alloc((size_t)2 * E * 8);
  int*  ghist  = (int*)alloc(2048 * 4);
  int*  bbase  = (int*)alloc(2064 * 4);
  int*  bcur   = (int*)alloc(2048 * 4);
  short* Wb    = (short*)alloc((size_t)6 * 16384 * 2);
  (void)ws_size; (void)n_in; (void)out_size;

  hipMemsetAsync(ghist, 0, 2048 * 4, stream);

  wconv_kernel<<<96, 256, 0, stream>>>(Wmn_dt, Wgn_dt, Ws_data, Wmn_td, Wgn_td, Ws_task, Wb);

  node_mfma_kernel<<<(N_DATA + 31) / 32, 256, 0, stream>>>(
      x_data, Wb, Wb + 16384, Wb + 32768,
      bmn_dt, bme_dt, bgn_dt, bge_dt, bs_data, bias_td,
      YG_dt, out, N_DATA);
  node_mfma_kernel<<<(N_TASK + 31) / 32, 256, 0, stream>>>(
      x_task, Wb + 3 * 16384, Wb + 4 * 16384, Wb + 5 * 16384,
      bmn_td, bme_td, bgn_td, bge_td, bs_task, bias_dt,
      YG_td, out + (size_t)N_DATA * D_DIM, N_TASK);

  hist0_kernel<<<256, 256, 0, stream>>>(dst_dt, dst_td, ghist, NBT, NB, E);
  bucket_scan_kernel<<<1, 256, 0, stream>>>(ghist, bbase, bcur, NB);
  sort_a_kernel<<<(E + 4095) / 4096, 256, 0, stream>>>(
      src_dt, dst_dt, ef_dt, src_td, dst_td, ef_td, bcur, eA, NBT, NB, E);

  gather_bucket_kernel<<<NB, 256, 0, stream>>>(
      YG_dt, YG_td, bbase, eA, Wme_dt, Wge_dt, Wme_td, Wge_td,
      out, NBT, N_TASK, N_DATA);
}

// Round 6
// 514.879 us; speedup vs baseline: 3.3816x; 3.3816x over previous
//
#include <hip/hip_runtime.h>
#include <hip/hip_bf16.h>
#include <cstdint>
#include <cstddef>

#define D_DIM 128

typedef __attribute__((ext_vector_type(8))) short short8;
typedef __attribute__((ext_vector_type(4))) float f32x4;

__device__ __forceinline__ float sigmoid_fast(float z) {
  return __builtin_amdgcn_rcpf(1.0f + __expf(-z));
}

__device__ __forceinline__ unsigned short f2bf(float f) {
  union { float f; unsigned u; } v; v.f = f;
  unsigned r = v.u + 0x7FFF + ((v.u >> 16) & 1);   // RNE
  return (unsigned short)(r >> 16);
}
__device__ __forceinline__ float bf_lo(unsigned u) { return __uint_as_float(u << 16); }
__device__ __forceinline__ float bf_hi(unsigned u) { return __uint_as_float(u & 0xFFFF0000u); }

// Convert 6 [128x128] f32 weight matrices to bf16, contiguous in dst.
__global__ __launch_bounds__(256) void wconv_kernel(
    const float* __restrict__ s0, const float* __restrict__ s1, const float* __restrict__ s2,
    const float* __restrict__ s3, const float* __restrict__ s4, const float* __restrict__ s5,
    short* __restrict__ dst) {
  int idx = blockIdx.x * 256 + threadIdx.x;
  int mat = idx >> 12;
  int pos = (idx & 4095) * 4;
  const float* s = (mat == 0) ? s0 : (mat == 1) ? s1 : (mat == 2) ? s2
                 : (mat == 3) ? s3 : (mat == 4) ? s4 : s5;
  float4 f = *(const float4*)(s + pos);
  short4 o;
  o.x = (short)f2bf(f.x); o.y = (short)f2bf(f.y);
  o.z = (short)f2bf(f.z); o.w = (short)f2bf(f.w);
  *(short4*)(dst + mat * 16384 + pos) = o;
}

// Per-node MFMA precompute. Block = 4 waves covering 32 nodes.
__global__ __launch_bounds__(256) void node_mfma_kernel(
    const float* __restrict__ x,
    const short* __restrict__ Wmnb, const short* __restrict__ Wgnb, const short* __restrict__ Wsb,
    const float* __restrict__ bmn, const float* __restrict__ bme,
    const float* __restrict__ bgn, const float* __restrict__ bge,
    const float* __restrict__ bs, const float* __restrict__ bias_other,
    unsigned int* __restrict__ YG, float* __restrict__ out_init, int n) {
  __shared__ unsigned sh[32][132];
  const int t = threadIdx.x;
  const int wave = t >> 6, lane = t & 63;
  const int q = lane >> 4, l15 = lane & 15;
  const int ng = wave >> 1;
  const int h = (wave & 1) * 64;
  const int base_node = blockIdx.x * 32;
  const int node_base = base_node + ng * 16;

  short8 a[4];
  {
    int m = node_base + l15;
    int mc = m < n ? m : (n - 1);
    const float* xrow = x + (size_t)mc * D_DIM;
#pragma unroll
    for (int ks = 0; ks < 4; ++ks) {
      float4 f0 = *(const float4*)(xrow + ks * 32 + q * 8);
      float4 f1 = *(const float4*)(xrow + ks * 32 + q * 8 + 4);
      union { short8 s; __hip_bfloat162 hh[4]; } u;
      u.hh[0] = __float22bfloat162_rn({f0.x, f0.y});
      u.hh[1] = __float22bfloat162_rn({f0.z, f0.w});
      u.hh[2] = __float22bfloat162_rn({f1.x, f1.y});
      u.hh[3] = __float22bfloat162_rn({f1.z, f1.w});
      a[ks] = u.s;
    }
  }

  f32x4 accY[4], accG[4], accS[4];
#pragma unroll
  for (int nt = 0; nt < 4; ++nt) { accY[nt] = {0,0,0,0}; accG[nt] = {0,0,0,0}; accS[nt] = {0,0,0,0}; }

#pragma unroll
  for (int nt = 0; nt < 4; ++nt) {
    const int row = h + nt * 16 + l15;
#pragma unroll
    for (int ks = 0; ks < 4; ++ks) {
      const int off = row * D_DIM + ks * 32 + q * 8;
      short8 bm  = *(const short8*)(Wmnb + off);
      short8 bg  = *(const short8*)(Wgnb + off);
      short8 bsw = *(const short8*)(Wsb + off);
      accY[nt] = __builtin_amdgcn_mfma_f32_16x16x32_bf16(a[ks], bm,  accY[nt], 0, 0, 0);
      accG[nt] = __builtin_amdgcn_mfma_f32_16x16x32_bf16(a[ks], bg,  accG[nt], 0, 0, 0);
      accS[nt] = __builtin_amdgcn_mfma_f32_16x16x32_bf16(a[ks], bsw, accS[nt], 0, 0, 0);
    }
  }

#pragma unroll
  for (int nt = 0; nt < 4; ++nt) {
    int d = h + nt * 16 + l15;
    float bmv = bmn[d] + bme[d];
    float bgv = bgn[d] + bge[d];
#pragma unroll
    for (int r = 0; r < 4; ++r) {
      union { __hip_bfloat162 hh; unsigned u; } pck;
      pck.hh = __float22bfloat162_rn({accY[nt][r] + bmv, accG[nt][r] + bgv});
      sh[ng * 16 + q * 4 + r][d] = pck.u;
    }
  }
  __syncthreads();
#pragma unroll
  for (int it = 0; it < 4; ++it) {
    int idx = (it * 256 + t) * 4;
    int nl = idx >> 7, dd = idx & 127;
    int node = base_node + nl;
    if (node < n)
      *(uint4*)(YG + (size_t)node * D_DIM + dd) = *(const uint4*)&sh[nl][dd];
  }
  __syncthreads();

  float* shf = (float*)sh;
#pragma unroll
  for (int nt = 0; nt < 4; ++nt) {
    int d = h + nt * 16 + l15;
    float bsv = bs[d];
#pragma unroll
    for (int r = 0; r < 4; ++r)
      shf[(ng * 16 + q * 4 + r) * 132 + d] = sigmoid_fast(accS[nt][r] + bsv) + 0.5f;
  }
  __syncthreads();
#pragma unroll
  for (int it = 0; it < 4; ++it) {
    int idx = (it * 256 + t) * 4;
    int nl = idx >> 7, dd = idx & 127;
    int node = base_node + nl;
    if (node < n) {
      float4 xv = *(const float4*)(x + (size_t)node * D_DIM + dd);
      float4 bo = *(const float4*)(bias_other + dd);
      const float* sp = &shf[nl * 132 + dd];
      float4 o;
      o.x = sp[0] * xv.x + bo.x;
      o.y = sp[1] * xv.y + bo.y;
      o.z = sp[2] * xv.z + bo.z;
      o.w = sp[3] * xv.w + bo.w;
      *(float4*)(out_init + (size_t)node * D_DIM + dd) = o;
    }
  }
}

// ---------- two-level counting sort of edges by combined dst ----------
// Coarse buckets: task 64 dsts/bucket (NBT), data 256 dsts/bucket (NBD).

__global__ __launch_bounds__(256) void hist0_kernel(
    const int* __restrict__ dst_dt, const int* __restrict__ dst_td,
    int* __restrict__ ghist, int nbt, int NB, int E) {
  __shared__ int lh[768];
  int t = threadIdx.x;
  lh[t] = 0; lh[t + 256] = 0; lh[t + 512] = 0;
  __syncthreads();
  for (int i = blockIdx.x * 256 + t; i < E; i += gridDim.x * 256) {
    atomicAdd(&lh[dst_dt[i] >> 6], 1);
    atomicAdd(&lh[nbt + (dst_td[i] >> 8)], 1);
  }
  __syncthreads();
#pragma unroll
  for (int k = 0; k < 3; ++k) {
    int b = t + k * 256;
    int c = lh[b];
    if (b < NB && c) atomicAdd(&ghist[b], c);
  }
}

__global__ __launch_bounds__(256) void bucket_scan_kernel(
    const int* __restrict__ ghist, int* __restrict__ bbase, int* __restrict__ bcur,
    int* __restrict__ offsets, int NB, int n_tot) {
  __shared__ int sc[256];
  int t = threadIdx.x;
  int i0 = t * 3;
  int c0 = (i0     < NB) ? ghist[i0]     : 0;
  int c1 = (i0 + 1 < NB) ? ghist[i0 + 1] : 0;
  int c2 = (i0 + 2 < NB) ? ghist[i0 + 2] : 0;
  int tot = c0 + c1 + c2;
  sc[t] = tot; __syncthreads();
  for (int s = 1; s < 256; s <<= 1) {
    int u = (t >= s) ? sc[t - s] : 0;
    __syncthreads(); sc[t] += u; __syncthreads();
  }
  int base = sc[t] - tot;
  if (i0     < NB) { bbase[i0]     = base;           bcur[i0]     = base; }
  if (i0 + 1 < NB) { bbase[i0 + 1] = base + c0;      bcur[i0 + 1] = base + c0; }
  if (i0 + 2 < NB) { bbase[i0 + 2] = base + c0 + c1; bcur[i0 + 2] = base + c0 + c1; }
  if (t == 255) { bbase[NB] = sc[255]; offsets[n_tot] = sc[255]; }
}

// Pass A: coarse partition, 8192 edges of each list per block.
__global__ __launch_bounds__(256) void sort_a_kernel(
    const int* __restrict__ src_dt, const int* __restrict__ dst_dt, const float* __restrict__ ef_dt,
    const int* __restrict__ src_td, const int* __restrict__ dst_td, const float* __restrict__ ef_td,
    int* __restrict__ bcur, int2* __restrict__ eA, int nbt, int NB, int E) {
  __shared__ int lh[768];
  __shared__ int lcur[768];
  int t = threadIdx.x;
  lh[t] = 0; lh[t + 256] = 0; lh[t + 512] = 0;
  __syncthreads();
  int e0 = blockIdx.x * 8192;
  int e1 = min(E, e0 + 8192);
  for (int i = e0 + t; i < e1; i += 256) {
    atomicAdd(&lh[dst_dt[i] >> 6], 1);
    atomicAdd(&lh[nbt + (dst_td[i] >> 8)], 1);
  }
  __syncthreads();
#pragma unroll
  for (int k = 0; k < 3; ++k) {
    int b = t + k * 256;
    int c = lh[b];
    if (b < NB && c) lcur[b] = atomicAdd(&bcur[b], c);
  }
  __syncthreads();
  for (int i = e0 + t; i < e1; i += 256) {
    int c = dst_dt[i];
    int bkt = c >> 6;
    int pos = atomicAdd(&lcur[bkt], 1);
    eA[pos] = make_int2(src_dt[i],
        (int)((__float_as_uint(ef_dt[i]) & 0xFFFFFF00u) | (unsigned)(c & 63)));
    int cd = dst_td[i];
    int bkt2 = nbt + (cd >> 8);
    int pos2 = atomicAdd(&lcur[bkt2], 1);
    eA[pos2] = make_int2(src_td[i],
        (int)((__float_as_uint(ef_td[i]) & 0xFFFFFF00u) | (unsigned)(cd & 255)));
  }
}

// Pass B: one block per bucket. 256-bin hist+scan; write final per-dst offsets;
// scatter entries within the bucket's contiguous (L2-resident) region.
__global__ __launch_bounds__(256) void sort_b_kernel(
    const int2* __restrict__ eA, const int* __restrict__ bbase,
    int* __restrict__ offsets, int2* __restrict__ eB,
    int nbt, int n_task, int n_tot) {
  __shared__ int lh[256], sc[256], lcur[256];
  int b = blockIdx.x, t = threadIdx.x;
  int base = bbase[b];
  int cnt = bbase[b + 1] - base;
  int c0, nloc;
  if (b < nbt) { c0 = b << 6; nloc = min(64, n_task - c0); }
  else { c0 = n_task + ((b - nbt) << 8); nloc = min(256, n_tot - c0); }
  lh[t] = 0; __syncthreads();
  for (int i = base + t; i < base + cnt; i += 256)
    atomicAdd(&lh[((unsigned)eA[i].y) & 255u], 1);
  __syncthreads();
  int v = lh[t];
  sc[t] = v; __syncthreads();
  for (int s = 1; s < 256; s <<= 1) {
    int u = (t >= s) ? sc[t - s] : 0;
    __syncthreads(); sc[t] += u; __syncthreads();
  }
  int ex = sc[t] - v;
  lcur[t] = base + ex;
  if (t < nloc) offsets[c0 + t] = base + ex;
  __syncthreads();
  for (int i = base + t; i < base + cnt; i += 256) {
    int2 e = eA[i];
    int pos = atomicAdd(&lcur[((unsigned)e.y) & 255u], 1);
    eB[pos] = e;
  }
}

// Combined gather: wave w<n_task -> task dst (dt conv), else data dst (td conv).
__device__ __forceinline__ void gstep(float2& acc, int sx, int ey,
                                      const unsigned* __restrict__ YG,
                                      int lane, float2 wme, float2 wge) {
  uint2 yg = *(const uint2*)(YG + (size_t)sx * D_DIM + 2 * lane);
  float f = __int_as_float(ey & (int)0xFFFFFF00);
  float g0 = sigmoid_fast(fmaf(f, wge.x, bf_hi(yg.x))) - 0.5f;
  float g1 = sigmoid_fast(fmaf(f, wge.y, bf_hi(yg.y))) - 0.5f;
  acc.x += fmaf(f, wme.x, bf_lo(yg.x)) * g0;
  acc.y += fmaf(f, wme.y, bf_lo(yg.y)) * g1;
}

__global__ __launch_bounds__(256) void gather_kernel(
    const unsigned* __restrict__ YG_dt, const unsigned* __restrict__ YG_td,
    const int* __restrict__ offsets, const int2* __restrict__ edata,
    const float* __restrict__ Wme_dt, const float* __restrict__ Wge_dt,
    const float* __restrict__ Wme_td, const float* __restrict__ Wge_td,
    float* __restrict__ out, int n_task, int n_data) {
  int w = (int)((blockIdx.x * 256u + threadIdx.x) >> 6);
  int lane = threadIdx.x & 63;
  if (w >= n_task + n_data) return;
  bool is_dt = w < n_task;
  const unsigned* YG = is_dt ? YG_dt : YG_td;
  const float* Wme = is_dt ? Wme_dt : Wme_td;
  const float* Wge = is_dt ? Wge_dt : Wge_td;
  size_t orow = is_dt ? (size_t)(n_data + w) : (size_t)(w - n_task);
  int beg = __builtin_amdgcn_readfirstlane(offsets[w]);
  int end = __builtin_amdgcn_readfirstlane(offsets[w + 1]);
  float2 wme = *(const float2*)(Wme + 2 * lane);
  float2 wge = *(const float2*)(Wge + 2 * lane);
  float* op = out + orow * D_DIM + 2 * lane;
  float2 acc = *(const float2*)op;
  int p = beg;
  for (; p + 8 <= end; p += 8) {
    // 4 wave-uniform int4 broadcasts cover 8 edge descriptors.
    int4 q0 = *(const int4*)&edata[p];
    int4 q1 = *(const int4*)&edata[p + 2];
    int4 q2 = *(const int4*)&edata[p + 4];
    int4 q3 = *(const int4*)&edata[p + 6];
    // Issue all 8 independent YG loads, then compute.
    uint2 y0 = *(const uint2*)(YG + (size_t)q0.x * D_DIM + 2 * lane);
    uint2 y1 = *(const uint2*)(YG + (size_t)q0.z * D_DIM + 2 * lane);
    uint2 y2 = *(const uint2*)(YG + (size_t)q1.x * D_DIM + 2 * lane);
    uint2 y3 = *(const uint2*)(YG + (size_t)q1.z * D_DIM + 2 * lane);
    uint2 y4 = *(const uint2*)(YG + (size_t)q2.x * D_DIM + 2 * lane);
    uint2 y5 = *(const uint2*)(YG + (size_t)q2.z * D_DIM + 2 * lane);
    uint2 y6 = *(const uint2*)(YG + (size_t)q3.x * D_DIM + 2 * lane);
    uint2 y7 = *(const uint2*)(YG + (size_t)q3.z * D_DIM + 2 * lane);
    int eys[8] = {q0.y, q0.w, q1.y, q1.w, q2.y, q2.w, q3.y, q3.w};
    uint2 ys[8] = {y0, y1, y2, y3, y4, y5, y6, y7};
#pragma unroll
    for (int j = 0; j < 8; ++j) {
      float f = __int_as_float(eys[j] & (int)0xFFFFFF00);
      float g0 = sigmoid_fast(fmaf(f, wge.x, bf_hi(ys[j].x))) - 0.5f;
      float g1 = sigmoid_fast(fmaf(f, wge.y, bf_hi(ys[j].y))) - 0.5f;
      acc.x += fmaf(f, wme.x, bf_lo(ys[j].x)) * g0;
      acc.y += fmaf(f, wme.y, bf_lo(ys[j].y)) * g1;
    }
  }
  for (; p + 2 <= end; p += 2) {
    int4 q0 = *(const int4*)&edata[p];
    gstep(acc, q0.x, q0.y, YG, lane, wme, wge);
    gstep(acc, q0.z, q0.w, YG, lane, wme, wge);
  }
  if (p < end) {
    int2 e0 = edata[p];
    gstep(acc, e0.x, e0.y, YG, lane, wme, wge);
  }
  acc.x = fmaxf(acc.x, 0.0f);
  acc.y = fmaxf(acc.y, 0.0f);
  *(float2*)op = acc;
}

extern "C" void kernel_launch(void* const* d_in, const int* in_sizes, int n_in,
                              void* d_out, int out_size, void* d_ws, size_t ws_size,
                              hipStream_t stream) {
  const float* x_data  = (const float*)d_in[0];
  const float* x_task  = (const float*)d_in[1];
  const int*   src_dt  = (const int*)d_in[2];
  const int*   dst_dt  = (const int*)d_in[3];
  const float* ef_dt   = (const float*)d_in[4];
  const int*   src_td  = (const int*)d_in[5];
  const int*   dst_td  = (const int*)d_in[6];
  const float* ef_td   = (const float*)d_in[7];
  const float* Wmn_dt  = (const float*)d_in[8];
  const float* bmn_dt  = (const float*)d_in[9];
  const float* Wme_dt  = (const float*)d_in[10];
  const float* bme_dt  = (const float*)d_in[11];
  const float* Wgn_dt  = (const float*)d_in[12];
  const float* bgn_dt  = (const float*)d_in[13];
  const float* Wge_dt  = (const float*)d_in[14];
  const float* bge_dt  = (const float*)d_in[15];
  const float* bias_dt = (const float*)d_in[16];
  const float* Wmn_td  = (const float*)d_in[17];
  const float* bmn_td  = (const float*)d_in[18];
  const float* Wme_td  = (const float*)d_in[19];
  const float* bme_td  = (const float*)d_in[20];
  const float* Wgn_td  = (const float*)d_in[21];
  const float* bgn_td  = (const float*)d_in[22];
  const float* Wge_td  = (const float*)d_in[23];
  const float* bge_td  = (const float*)d_in[24];
  const float* bias_td = (const float*)d_in[25];
  const float* Ws_data = (const float*)d_in[26];
  const float* bs_data = (const float*)d_in[27];
  const float* Ws_task = (const float*)d_in[28];
  const float* bs_task = (const float*)d_in[29];
  float* out = (float*)d_out;

  const int N_DATA = in_sizes[0] / D_DIM;   // 100000
  const int N_TASK = in_sizes[1] / D_DIM;   // 20000
  const int E = in_sizes[2];                // 1000000
  const int N_TOT = N_TASK + N_DATA;
  const int NBT = (N_TASK + 63) >> 6;       // 313 task buckets (64 dsts each)
  const int NBD = (N_DATA + 255) >> 8;      // 391 data buckets (256 dsts each)
  const int NB = NBT + NBD;                 // 704

  char* ws = (char*)d_ws;
  size_t off = 0;
  auto alloc = [&](size_t bytes) { void* p = ws + off; off += (bytes + 255) & ~(size_t)255; return p; };
  unsigned int* YG_dt = (unsigned int*)alloc((size_t)N_DATA * D_DIM * 4);
  unsigned int* YG_td = (unsigned int*)alloc((size_t)N_TASK * D_DIM * 4);
  int2* eA     = (int2*)alloc((size_t)2 * E * 8);
  int2* eB     = (int2*)alloc((size_t)2 * E * 8);
  int*  offs   = (int*)alloc((size_t)(N_TOT + 1) * 4);
  int*  ghist  = (int*)alloc(768 * 4);
  int*  bbase  = (int*)alloc(768 * 4);
  int*  bcur   = (int*)alloc(768 * 4);
  short* Wb    = (short*)alloc((size_t)6 * 16384 * 2);
  (void)ws_size; (void)n_in; (void)out_size;

  hipMemsetAsync(ghist, 0, 768 * 4, stream);

  wconv_kernel<<<96, 256, 0, stream>>>(Wmn_dt, Wgn_dt, Ws_data, Wmn_td, Wgn_td, Ws_task, Wb);

  node_mfma_kernel<<<(N_DATA + 31) / 32, 256, 0, stream>>>(
      x_data, Wb, Wb + 16384, Wb + 32768,
      bmn_dt, bme_dt, bgn_dt, bge_dt, bs_data, bias_td,
      YG_dt, out, N_DATA);
  node_mfma_kernel<<<(N_TASK + 31) / 32, 256, 0, stream>>>(
      x_task, Wb + 3 * 16384, Wb + 4 * 16384, Wb + 5 * 16384,
      bmn_td, bme_td, bgn_td, bge_td, bs_task, bias_dt,
      YG_td, out + (size_t)N_DATA * D_DIM, N_TASK);

  hist0_kernel<<<256, 256, 0, stream>>>(dst_dt, dst_td, ghist, NBT, NB, E);
  bucket_scan_kernel<<<1, 256, 0, stream>>>(ghist, bbase, bcur, offs, NB, N_TOT);
  sort_a_kernel<<<(E + 8191) / 8192, 256, 0, stream>>>(
      src_dt, dst_dt, ef_dt, src_td, dst_td, ef_td, bcur, eA, NBT, NB, E);
  sort_b_kernel<<<NB, 256, 0, stream>>>(eA, bbase, offs, eB, NBT, N_TASK, N_TOT);

  gather_kernel<<<(N_TOT + 3) / 4, 256, 0, stream>>>(
      YG_dt, YG_td, offs, eB, Wme_dt, Wge_dt, Wme_td, Wge_td, out, N_TASK, N_DATA);
}